// Round 5
// baseline (231.596 us; speedup 1.0000x reference)
//
#include <hip/hip_runtime.h>
#include <cstddef>
#include <cstdint>

#define B_ 8
#define CIN_ 64
#define COUT_ 64
#define N_ 16384
#define K_ 9
#define L_ 32768
#define TT 128
#define MROWS 136   // rows m0 = t0-2 .. t0+133

typedef __attribute__((ext_vector_type(8))) short  short8v;
typedef __attribute__((ext_vector_type(4))) float  float4v;

static __device__ __forceinline__ uint16_t f2bf(float f) {
    uint32_t u = __float_as_uint(f);
    uint32_t r = (u + 0x7FFFu + ((u >> 16) & 1u)) >> 16;   // RNE
    return (uint16_t)r;
}

// weight [o][c][k] f32 -> frag-ordered bf16. frag f = (jg*2+ks)*4 + wv;
// lane holds A[row=o=wv*16+(l&15)][c = ks*32 + (l>>4)*8 + e], tap = jg<5 ? 2*jg : 2*(jg-5)+1
__global__ __launch_bounds__(256) void w_prep(const float* __restrict__ w,
                                              uint16_t* __restrict__ wp) {
    int i = blockIdx.x * 256 + threadIdx.x;
    if (i >= 72 * 64) return;
    int lane = i & 63, f = i >> 6;
    int wv = f & 3, ks = (f >> 2) & 1, jg = f >> 3;
    int p = jg >= 5 ? 1 : 0;
    int j = p ? jg - 5 : jg;
    int ktap = 2 * j + p;
    int o  = wv * 16 + (lane & 15);
    int cb = ks * 32 + (lane >> 4) * 8;
    uint16_t* dst = wp + (size_t)f * 512 + lane * 8;
#pragma unroll
    for (int e = 0; e < 8; ++e)
        dst[e] = f2bf(w[((size_t)o * CIN_ + cb + e) * K_ + ktap]);
}

// Fused, low-pressure: gate -> {x half -> f32 LDS -> bf16 swizzled LDS} x2 -> 9 tap-GEMMs.
// No register arrays live across barriers (R3 spilled 370 MB of scratch doing that).
__global__ __launch_bounds__(256, 4) void wct_fused2(
    const float* __restrict__ x, const float* __restrict__ coords,
    const float* __restrict__ sigma_p, const uint16_t* __restrict__ wp,
    float* __restrict__ out)
{
    __shared__ float                  tile_f[32][137];    // 17548 B; pitch 137 -> 2-way col reads
    __shared__ __align__(16) uint16_t xs[MROWS * 64];     // 17408 B; [m][c] bf16, XOR-swizzled
    __shared__ float                  s_lds[9][128];      // 4608 B gate values

    const int t0   = blockIdx.x * TT;
    const int b    = blockIdx.y;
    const int tid  = threadIdx.x;
    const int lane = tid & 63;
    const int wv   = tid >> 6;
    const int tcol = lane & 15;
    const int kgrp = lane >> 4;
    const int m0   = t0 - 2;                              // m0 & 7 == 6

    const float* xb = x + (size_t)b * CIN_ * N_;
    const bool fast = (blockIdx.x != 0) & ((int)blockIdx.x != (N_ / TT - 1));

    // ---- phase 0: coords gate s[jg][tl] (pure global reads + VALU) ----
    {
        const float* cb = coords + (size_t)b * 3 * L_;
        const float inv_sigma = 1.0f / sigma_p[0];
#pragma unroll
        for (int i = 0; i < 5; ++i) {
            int slot = tid + 256 * i;
            if (slot < 1152) {
                int jg = slot >> 7, tl = slot & 127;
                int p = jg >= 5 ? 1 : 0;
                int j = p ? jg - 5 : jg;
                int t = t0 + tl;
                int m = t + j - (p ? 1 : 2);
                int lout = 2 * t + p;
                bool valid = (m >= 0) & (m < N_);
                int pc = 2 * m;
                pc = pc < 0 ? 0 : (pc > L_ - 1 ? L_ - 1 : pc);
                float d0 = cb[pc] - cb[lout];
                float d1 = cb[L_ + pc] - cb[L_ + lout];
                float d2 = cb[2 * L_ + pc] - cb[2 * L_ + lout];
                float sv = fmaxf(1.0f - sqrtf(d0 * d0 + d1 * d1 + d2 * d2) * inv_sigma, 0.0f);
                s_lds[jg][tl] = valid ? sv : 0.0f;
            }
        }
    }

    // ---- phases 1..2 twice: stage c-half into f32 tile, convert into swizzled bf16 ----
#pragma unroll
    for (int half = 0; half < 2; ++half) {
        const float* xh = xb + (size_t)(half * 32) * N_;
        // load -> LDS immediately (transient 2 regs per element, released per iter)
#pragma unroll
        for (int i = 0; i < 9; ++i) {
            int idx = tid + 256 * i;                 // 32 c-rows x 68 float2 = 2176
            if (idx < 2176) {
                int c  = idx / 68;
                int mh = idx - c * 68;
                int gm = m0 + 2 * mh;
                float v0, v1;
                if (fast) {
                    float2 v = *(const float2*)(xh + (size_t)c * N_ + gm);
                    v0 = v.x; v1 = v.y;
                } else {                              // edge blocks: clamp (gate zeroes these taps)
                    int g0 = min(max(gm, 0), N_ - 1);
                    int g1 = min(max(gm + 1, 0), N_ - 1);
                    v0 = xh[(size_t)c * N_ + g0];
                    v1 = xh[(size_t)c * N_ + g1];
                }
                tile_f[c][2 * mh]     = v0;
                tile_f[c][2 * mh + 1] = v1;
            }
        }
        __syncthreads();
        // convert: read two f32 columns, pack to bf16x2, swizzled dword store
#pragma unroll
        for (int i = 0; i < 9; ++i) {
            int idx = tid + 256 * i;                 // 136 m x 16 c-pairs = 2176
            if (idx < 2176) {
                int m = idx >> 4, cp = idx & 15;
                uint32_t pk = (uint32_t)f2bf(tile_f[2 * cp][m]) |
                              ((uint32_t)f2bf(tile_f[2 * cp + 1][m]) << 16);
                int key = ((m + 6) & 7) << 4;        // == ((m0+m)&7)<<4
                *(uint32_t*)((char*)xs + m * 128 + ((half * 64 + cp * 4) ^ key)) = pk;
            }
        }
        __syncthreads();
    }

    // ---- compute: joff-outer; taps jgE=joff (even) and jgO=joff+4 (odd) share B-frags ----
    float4v accE[8], accO[8];
#pragma unroll
    for (int nf = 0; nf < 8; ++nf) { accE[nf] = (float4v){0,0,0,0}; accO[nf] = (float4v){0,0,0,0}; }

#pragma unroll
    for (int joff = 0; joff < 5; ++joff) {
        const int jgE = joff;
        const int jgO = joff + 4;                // odd tap, valid only for joff>=1
        short8v wE0 = *(const short8v*)(wp + (size_t)((jgE * 2 + 0) * 4 + wv) * 512 + lane * 8);
        short8v wE1 = *(const short8v*)(wp + (size_t)((jgE * 2 + 1) * 4 + wv) * 512 + lane * 8);
        short8v wO0 = *(const short8v*)(wp + (size_t)((jgO * 2 + 0) * 4 + wv) * 512 + lane * 8);
        short8v wO1 = *(const short8v*)(wp + (size_t)((jgO * 2 + 1) * 4 + wv) * 512 + lane * 8);

        const int rowb = tcol + joff;
        const int key  = ((rowb + 6) & 7) << 4;  // 16*nf preserves key (16 % 8 == 0)
        const char* bpA = (const char*)xs + rowb * 128 + ((kgrp * 16) ^ key);
        const char* bpB = (const char*)xs + rowb * 128 + ((kgrp * 16 + 64) ^ key);

#pragma unroll
        for (int nf = 0; nf < 8; ++nf) {
            short8v B0 = *(const short8v*)(bpA + nf * 2048);
            short8v B1 = *(const short8v*)(bpB + nf * 2048);
            float4v g = (float4v){0,0,0,0};
            g = __builtin_amdgcn_mfma_f32_16x16x32_bf16(wE0, B0, g, 0, 0, 0);
            g = __builtin_amdgcn_mfma_f32_16x16x32_bf16(wE1, B1, g, 0, 0, 0);
            float sE = s_lds[jgE][nf * 16 + tcol];
            accE[nf][0] += sE * g[0]; accE[nf][1] += sE * g[1];
            accE[nf][2] += sE * g[2]; accE[nf][3] += sE * g[3];
            if (joff >= 1) {
                float4v h = (float4v){0,0,0,0};
                h = __builtin_amdgcn_mfma_f32_16x16x32_bf16(wO0, B0, h, 0, 0, 0);
                h = __builtin_amdgcn_mfma_f32_16x16x32_bf16(wO1, B1, h, 0, 0, 0);
                float sO = s_lds[jgO][nf * 16 + tcol];
                accO[nf][0] += sO * h[0]; accO[nf][1] += sO * h[1];
                accO[nf][2] += sO * h[2]; accO[nf][3] += sO * h[3];
            }
        }
    }

    // ---- store: lane holds o = wv*16 + kgrp*4 + r, t = t0 + nf*16 + tcol ----
#pragma unroll
    for (int nf = 0; nf < 8; ++nf) {
        int t = t0 + nf * 16 + tcol;
#pragma unroll
        for (int r = 0; r < 4; ++r) {
            int o = wv * 16 + kgrp * 4 + r;
            *(float2*)(out + ((size_t)(b * COUT_ + o)) * L_ + 2 * t) =
                make_float2(accE[nf][r], accO[nf][r]);
        }
    }
}

extern "C" void kernel_launch(void* const* d_in, const int* in_sizes, int n_in,
                              void* d_out, int out_size, void* d_ws, size_t ws_size,
                              hipStream_t stream) {
    const float* x      = (const float*)d_in[0];
    const float* coords = (const float*)d_in[1];
    const float* sigma  = (const float*)d_in[2];
    const float* w      = (const float*)d_in[3];
    float* out = (float*)d_out;

    uint16_t* wp = (uint16_t*)d_ws;              // 72 frags x 512 elems x 2B = 73728 B
    w_prep<<<dim3(18), 256, 0, stream>>>(w, wp);
    wct_fused2<<<dim3(N_ / TT, B_), 256, 0, stream>>>(x, coords, sigma, wp, out);
}

// Round 8
// 124.416 us; speedup vs baseline: 1.8615x; 1.8615x over previous
//
#include <hip/hip_runtime.h>
#include <cstddef>
#include <cstdint>

#define B_ 8
#define CIN_ 64
#define COUT_ 64
#define N_ 16384
#define K_ 9
#define L_ 32768
#define TT 128
#define MROWS 136   // rows m0 = t0-2 .. t0+133

typedef __attribute__((ext_vector_type(8))) short  short8v;
typedef __attribute__((ext_vector_type(4))) float  float4v;

static __device__ __forceinline__ uint16_t f2bf(float f) {
    uint32_t u = __float_as_uint(f);
    uint32_t r = (u + 0x7FFFu + ((u >> 16) & 1u)) >> 16;   // RNE
    return (uint16_t)r;
}

// weight [o][c][k] f32 -> frag-ordered bf16. frag f = (jg*2+ks)*4 + wv;
// lane holds A[row=o=wv*16+(l&15)][c = ks*32 + (l>>4)*8 + e], tap = jg<5 ? 2*jg : 2*(jg-5)+1
__global__ __launch_bounds__(256) void w_prep(const float* __restrict__ w,
                                              uint16_t* __restrict__ wp) {
    int i = blockIdx.x * 256 + threadIdx.x;
    if (i >= 72 * 64) return;
    int lane = i & 63, f = i >> 6;
    int wv = f & 3, ks = (f >> 2) & 1, jg = f >> 3;
    int p = jg >= 5 ? 1 : 0;
    int j = p ? jg - 5 : jg;
    int ktap = 2 * j + p;
    int o  = wv * 16 + (lane & 15);
    int cb = ks * 32 + (lane >> 4) * 8;
    uint16_t* dst = wp + (size_t)f * 512 + lane * 8;
#pragma unroll
    for (int e = 0; e < 8; ++e)
        dst[e] = f2bf(w[((size_t)o * CIN_ + cb + e) * K_ + ktap]);
}

// Fused: gate -> {x half -> f32 LDS -> bf16 swizzled LDS} x2 -> 9 tap-GEMMs.
// joff loop is NOT unrolled: R3/R5 fully-unrolled version hoisted all 20
// W-fragments (80 VGPRs) -> unified-file split (VGPR_Count=64) -> accumulator
// scratch spill (~117 MB extra FETCH / ~262 MB extra WRITE per launch).
__global__ __launch_bounds__(256, 4) void wct_fused3(
    const float* __restrict__ x, const float* __restrict__ coords,
    const float* __restrict__ sigma_p, const uint16_t* __restrict__ wp,
    float* __restrict__ out)
{
    __shared__ float                  tile_f[32][137];    // pitch 137: 2-way max col reads
    __shared__ __align__(16) uint16_t xs[MROWS * 64];     // [m][c] bf16, XOR-swizzled rows
    __shared__ float                  s_lds[9][128];      // gate values

    const int t0   = blockIdx.x * TT;
    const int b    = blockIdx.y;
    const int tid  = threadIdx.x;
    const int lane = tid & 63;
    const int wv   = tid >> 6;
    const int tcol = lane & 15;
    const int kgrp = lane >> 4;
    const int m0   = t0 - 2;                              // m0 & 7 == 6

    const float* xb = x + (size_t)b * CIN_ * N_;
    const bool fast = (blockIdx.x != 0) & ((int)blockIdx.x != (N_ / TT - 1));

    // ---- phase 0: coords gate s[jg][tl] ----
    {
        const float* cb = coords + (size_t)b * 3 * L_;
        const float inv_sigma = 1.0f / sigma_p[0];
#pragma unroll
        for (int i = 0; i < 5; ++i) {
            int slot = tid + 256 * i;
            if (slot < 1152) {
                int jg = slot >> 7, tl = slot & 127;
                int p = jg >= 5 ? 1 : 0;
                int j = p ? jg - 5 : jg;
                int t = t0 + tl;
                int m = t + j - (p ? 1 : 2);
                int lout = 2 * t + p;
                bool valid = (m >= 0) & (m < N_);
                int pc = 2 * m;
                pc = pc < 0 ? 0 : (pc > L_ - 1 ? L_ - 1 : pc);
                float d0 = cb[pc] - cb[lout];
                float d1 = cb[L_ + pc] - cb[L_ + lout];
                float d2 = cb[2 * L_ + pc] - cb[2 * L_ + lout];
                float sv = fmaxf(1.0f - sqrtf(d0 * d0 + d1 * d1 + d2 * d2) * inv_sigma, 0.0f);
                s_lds[jg][tl] = valid ? sv : 0.0f;
            }
        }
    }

    // ---- stage each c-half: global f32 -> tile_f -> packed bf16 swizzled xs ----
#pragma unroll
    for (int half = 0; half < 2; ++half) {
        const float* xh = xb + (size_t)(half * 32) * N_;
#pragma unroll
        for (int i = 0; i < 9; ++i) {
            int idx = tid + 256 * i;                 // 32 c-rows x 68 float2 = 2176
            if (idx < 2176) {
                int c  = idx / 68;
                int mh = idx - c * 68;
                int gm = m0 + 2 * mh;
                float v0, v1;
                if (fast) {
                    float2 v = *(const float2*)(xh + (size_t)c * N_ + gm);
                    v0 = v.x; v1 = v.y;
                } else {                              // edge blocks: clamp (gate zeroes these taps)
                    int g0 = min(max(gm, 0), N_ - 1);
                    int g1 = min(max(gm + 1, 0), N_ - 1);
                    v0 = xh[(size_t)c * N_ + g0];
                    v1 = xh[(size_t)c * N_ + g1];
                }
                tile_f[c][2 * mh]     = v0;
                tile_f[c][2 * mh + 1] = v1;
            }
        }
        __syncthreads();
#pragma unroll
        for (int i = 0; i < 9; ++i) {
            int idx = tid + 256 * i;                 // 136 m x 16 c-pairs = 2176
            if (idx < 2176) {
                int m = idx >> 4, cp = idx & 15;
                uint32_t pk = (uint32_t)f2bf(tile_f[2 * cp][m]) |
                              ((uint32_t)f2bf(tile_f[2 * cp + 1][m]) << 16);
                int key = ((m + 6) & 7) << 4;        // == ((m0+m)&7)<<4
                *(uint32_t*)((char*)xs + m * 128 + ((half * 64 + cp * 4) ^ key)) = pk;
            }
        }
        __syncthreads();
    }

    // ---- compute: joff-outer (runtime loop!); even tap jgE=joff and odd tap
    // jgO=joff+4 share the B-fragments; only 4 W-frags live at a time ----
    float4v accE[8], accO[8];
#pragma unroll
    for (int nf = 0; nf < 8; ++nf) { accE[nf] = (float4v){0,0,0,0}; accO[nf] = (float4v){0,0,0,0}; }

#pragma unroll 1
    for (int joff = 0; joff < 5; ++joff) {
        const int jgE = joff;
        const int jgO = joff + 4;                // odd tap, valid only for joff>=1
        short8v wE0 = *(const short8v*)(wp + (size_t)((jgE * 2 + 0) * 4 + wv) * 512 + lane * 8);
        short8v wE1 = *(const short8v*)(wp + (size_t)((jgE * 2 + 1) * 4 + wv) * 512 + lane * 8);
        short8v wO0 = *(const short8v*)(wp + (size_t)((jgO * 2 + 0) * 4 + wv) * 512 + lane * 8);
        short8v wO1 = *(const short8v*)(wp + (size_t)((jgO * 2 + 1) * 4 + wv) * 512 + lane * 8);

        const int rowb = tcol + joff;
        const int key  = ((rowb + 6) & 7) << 4;  // 16*nf preserves key (16 % 8 == 0)
        const char* bpA = (const char*)xs + rowb * 128 + ((kgrp * 16) ^ key);
        const char* bpB = (const char*)xs + rowb * 128 + ((kgrp * 16 + 64) ^ key);

#pragma unroll
        for (int nf = 0; nf < 8; ++nf) {
            short8v B0 = *(const short8v*)(bpA + nf * 2048);
            short8v B1 = *(const short8v*)(bpB + nf * 2048);
            float4v g = (float4v){0,0,0,0};
            g = __builtin_amdgcn_mfma_f32_16x16x32_bf16(wE0, B0, g, 0, 0, 0);
            g = __builtin_amdgcn_mfma_f32_16x16x32_bf16(wE1, B1, g, 0, 0, 0);
            float sE = s_lds[jgE][nf * 16 + tcol];
            accE[nf][0] += sE * g[0]; accE[nf][1] += sE * g[1];
            accE[nf][2] += sE * g[2]; accE[nf][3] += sE * g[3];
            if (joff >= 1) {
                float4v h = (float4v){0,0,0,0};
                h = __builtin_amdgcn_mfma_f32_16x16x32_bf16(wO0, B0, h, 0, 0, 0);
                h = __builtin_amdgcn_mfma_f32_16x16x32_bf16(wO1, B1, h, 0, 0, 0);
                float sO = s_lds[jgO][nf * 16 + tcol];
                accO[nf][0] += sO * h[0]; accO[nf][1] += sO * h[1];
                accO[nf][2] += sO * h[2]; accO[nf][3] += sO * h[3];
            }
        }
    }

    // ---- store: lane holds o = wv*16 + kgrp*4 + r, t = t0 + nf*16 + tcol ----
#pragma unroll
    for (int nf = 0; nf < 8; ++nf) {
        int t = t0 + nf * 16 + tcol;
#pragma unroll
        for (int r = 0; r < 4; ++r) {
            int o = wv * 16 + kgrp * 4 + r;
            *(float2*)(out + ((size_t)(b * COUT_ + o)) * L_ + 2 * t) =
                make_float2(accE[nf][r], accO[nf][r]);
        }
    }
}

extern "C" void kernel_launch(void* const* d_in, const int* in_sizes, int n_in,
                              void* d_out, int out_size, void* d_ws, size_t ws_size,
                              hipStream_t stream) {
    const float* x      = (const float*)d_in[0];
    const float* coords = (const float*)d_in[1];
    const float* sigma  = (const float*)d_in[2];
    const float* w      = (const float*)d_in[3];
    float* out = (float*)d_out;

    uint16_t* wp = (uint16_t*)d_ws;              // 72 frags x 512 elems x 2B = 73728 B
    w_prep<<<dim3(18), 256, 0, stream>>>(w, wp);
    wct_fused3<<<dim3(N_ / TT, B_), 256, 0, stream>>>(x, coords, sigma, wp, out);
}